// Round 7
// baseline (468.309 us; speedup 1.0000x reference)
//
#include <hip/hip_runtime.h>
#include <math.h>

typedef _Float16 f16;
typedef f16 f16x8 __attribute__((ext_vector_type(8)));
typedef float f32x4 __attribute__((ext_vector_type(4)));
typedef unsigned int u32;
typedef u32 u32x2 __attribute__((ext_vector_type(2)));
typedef u32 u32x4 __attribute__((ext_vector_type(4)));

constexpr int H = 512, W = 512;
constexpr int TY = 16;                  // output rows per block
constexpr int TW = 256;                 // output cols per block
constexpr int NBANDS = H / TY;          // 32
constexpr int GXB = W / TW;             // 2
constexpr int NPLANES = 96;             // 32 batch * 3 ch
constexpr int NBLK = GXB * NBANDS * NPLANES;   // 6144
constexpr int NTILES_V = 17;            // halo col tiles: 272 >= 266
constexpr int NTILES_H = TW / 16;       // 16
constexpr int VP = 280;                 // f16 pitch: 560 B = 140 words == 4 (mod 8) -> 8-bank spread on b128
constexpr double NTOT = 25165824.0;
constexpr float C1 = 1.0e-4f;
constexpr float C2 = 9.0e-4f;

struct Wts { float w[11]; };

__device__ __forceinline__ u32 pk(float lo, float hi) {
    return __builtin_bit_cast(u32, __builtin_amdgcn_cvt_pkrtz(lo, hi));
}

// Vertical-conv tile via mfma(A=data, B=Toeplitz). Lane(tr,g) holds
// A[tr][k0+j] = pre[row y0-5+k0+j][halo col 16t+tr]; zero-band rows k>=26 are
// skipped (their B rows are exactly zero) -> zero fragments, no loads.
template<bool MASK, bool YEDGE>
__device__ __forceinline__ void stage_v(const float* __restrict__ p1,
                                        const float* __restrict__ p2,
                                        f16 (&vc)[4][TY][VP], const f16x8 tw,
                                        const int (&rowbase)[8], const float (&ymul)[8],
                                        int x, int t, int tr, int g, int k0)
{
    int xc = x; float xm = 1.f;
    if (MASK) {
        const bool xok = (unsigned)x < (unsigned)W;
        xc = xok ? x : 0;
        xm = xok ? 1.f : 0.f;
    }
    u32 pa[4], pb[4], pqa[4], pqb[4];
    #pragma unroll
    for (int jp = 0; jp < 4; ++jp) {
        float a0 = 0.f, b0 = 0.f, q0 = 0.f, r0 = 0.f;
        float a1 = 0.f, b1 = 0.f, q1 = 0.f, r1 = 0.f;
        if (k0 + 2 * jp < 26) {            // per-lane: g==3 keeps only jp==0
            const int j0 = 2 * jp, j1 = 2 * jp + 1;
            float v1a = p1[rowbase[j0] + xc], v2a = p2[rowbase[j0] + xc];
            float v1b = p1[rowbase[j1] + xc], v2b = p2[rowbase[j1] + xc];
            if (MASK || YEDGE) {
                float m0 = 1.f, m1 = 1.f;
                if (MASK)  { m0 = xm; m1 = xm; }
                if (YEDGE) { m0 *= ymul[j0]; m1 *= ymul[j1]; }
                v1a *= m0; v2a *= m0; v1b *= m1; v2b *= m1;
            }
            a0 = v1a + v2a; b0 = v1a - v2a; q0 = a0 * a0; r0 = b0 * b0;
            a1 = v1b + v2b; b1 = v1b - v2b; q1 = a1 * a1; r1 = b1 * b1;
        }
        pa[jp]  = pk(a0, a1);  pb[jp]  = pk(b0, b1);
        pqa[jp] = pk(q0, q1);  pqb[jp] = pk(r0, r1);
    }
    const f16x8 fA  = __builtin_bit_cast(f16x8, (u32x4){pa[0],  pa[1],  pa[2],  pa[3]});
    const f16x8 fB  = __builtin_bit_cast(f16x8, (u32x4){pb[0],  pb[1],  pb[2],  pb[3]});
    const f16x8 fQa = __builtin_bit_cast(f16x8, (u32x4){pqa[0], pqa[1], pqa[2], pqa[3]});
    const f16x8 fQb = __builtin_bit_cast(f16x8, (u32x4){pqb[0], pqb[1], pqb[2], pqb[3]});

    const f32x4 z4 = { 0.f, 0.f, 0.f, 0.f };
    const f32x4 dA  = __builtin_amdgcn_mfma_f32_16x16x32_f16(fA,  tw, z4, 0, 0, 0);
    const f32x4 dB  = __builtin_amdgcn_mfma_f32_16x16x32_f16(fB,  tw, z4, 0, 0, 0);
    const f32x4 dQa = __builtin_amdgcn_mfma_f32_16x16x32_f16(fQa, tw, z4, 0, 0, 0);
    const f32x4 dQb = __builtin_amdgcn_mfma_f32_16x16x32_f16(fQb, tw, z4, 0, 0, 0);

    // D lane(tr,g) reg i -> output row tr, halo col 16t+4g+i (m89 C/D layout,
    // refcheck-verified in round 5). One b64 store per plane.
    const int cb = 16 * t + 4 * g;
    { u32x2 v = { pk(dA[0],  dA[1]),  pk(dA[2],  dA[3])  }; *(u32x2*)&vc[0][tr][cb] = v; }
    { u32x2 v = { pk(dB[0],  dB[1]),  pk(dB[2],  dB[3])  }; *(u32x2*)&vc[1][tr][cb] = v; }
    { u32x2 v = { pk(dQa[0], dQa[1]), pk(dQa[2], dQa[3]) }; *(u32x2*)&vc[2][tr][cb] = v; }
    { u32x2 v = { pk(dQb[0], dQb[1]), pk(dQb[2], dQb[3]) }; *(u32x2*)&vc[3][tr][cb] = v; }
}

template<bool YEDGE>
__device__ __forceinline__ void stage_v_all(const float* __restrict__ p1,
                                            const float* __restrict__ p2,
                                            f16 (&vc)[4][TY][VP], const f16x8 tw,
                                            int y0, int x0, int xb,
                                            int tr, int g, int k0, int wave)
{
    int rowbase[8]; float ymul[8];
    #pragma unroll
    for (int j = 0; j < 8; ++j) {
        const int y = y0 - 5 + k0 + j;
        if (YEDGE) {
            const bool yok = (unsigned)y < (unsigned)H;
            rowbase[j] = (yok ? y : 0) * W;
            ymul[j] = yok ? 1.f : 0.f;
        } else {
            rowbase[j] = y * W;
            ymul[j] = 1.f;
        }
    }
    const int mt = xb ? (NTILES_V - 1) : 0;   // the single x-masked tile
    for (int t = wave; t < NTILES_V; t += 8) {
        const int x = x0 + 16 * t + tr - 5;
        if (t == mt) stage_v<true,  YEDGE>(p1, p2, vc, tw, rowbase, ymul, x, t, tr, g, k0);
        else         stage_v<false, YEDGE>(p1, p2, vc, tw, rowbase, ymul, x, t, tr, g, k0);
    }
}

__global__ __launch_bounds__(512, 8)
void ssim_main(const float* __restrict__ img1, const float* __restrict__ img2,
               float* __restrict__ part, Wts wts)
{
    __shared__ __align__(16) f16 vc[4][TY][VP];   // 35,840 B -> 4 blocks/CU
    __shared__ __align__(16) f16 Tb[16][40];
    __shared__ float red[8];

    const int tid  = threadIdx.x;
    const int lane = tid & 63;
    const int wave = tid >> 6;
    const int tr   = lane & 15;
    const int g    = lane >> 4;
    const int k0   = g * 8;

    // Toeplitz T[idx][k] = w[k-idx] (zero band kills k>=26 garbage).
    for (int i = tid; i < 640; i += 512) {
        const int m = i / 40, k = i - m * 40, d = k - m;
        Tb[m][k] = (d >= 0 && d <= 10) ? (f16)wts.w[d] : (f16)0.0f;
    }
    __syncthreads();
    const f16x8 tw = *(const f16x8*)&Tb[tr][k0];

    // XCD swizzle: each XCD gets 12 contiguous planes (2 MB/plane-pair < 4 MB
    // L2) -> band halos and plane data reused in the local L2. Perf-only.
    const int id    = blockIdx.x;
    const int gb    = (id & 7) * (NBLK / 8) + (id >> 3);
    const int plane = gb >> 6;            // 64 blocks per plane
    const int rem   = gb & 63;
    const int band  = rem >> 1;
    const int xb    = rem & 1;

    const int y0 = band * TY;
    const int x0 = xb * TW;
    const size_t poff = (size_t)plane * (size_t)(H * W);
    const float* p1 = img1 + poff;
    const float* p2 = img2 + poff;

    if (band == 0 || band == NBANDS - 1)
        stage_v_all<true>(p1, p2, vc, tw, y0, x0, xb, tr, g, k0, wave);
    else
        stage_v_all<false>(p1, p2, vc, tw, y0, x0, xb, tr, g, k0, wave);
    __syncthreads();

    // Stage H: mfma(A=Toeplitz, B=vc rows) + SSIM map. Lane(tr,g) holds
    // B[k0+j][tr] = vc[row tr][cb+k0+j] -> one ds_read_b128 per plane.
    const f32x4 z4 = { 0.f, 0.f, 0.f, 0.f };
    float local = 0.f;
    #pragma unroll
    for (int i = 0; i < NTILES_H / 8; ++i) {
        const int cb = 16 * (wave + 8 * i);
        const f16x8 bA  = *(const f16x8*)&vc[0][tr][cb + k0];
        const f16x8 bB  = *(const f16x8*)&vc[1][tr][cb + k0];
        const f16x8 bQa = *(const f16x8*)&vc[2][tr][cb + k0];
        const f16x8 bQb = *(const f16x8*)&vc[3][tr][cb + k0];
        const f32x4 rA  = __builtin_amdgcn_mfma_f32_16x16x32_f16(tw, bA,  z4, 0, 0, 0);
        const f32x4 rB  = __builtin_amdgcn_mfma_f32_16x16x32_f16(tw, bB,  z4, 0, 0, 0);
        const f32x4 rQa = __builtin_amdgcn_mfma_f32_16x16x32_f16(tw, bQa, z4, 0, 0, 0);
        const f32x4 rQb = __builtin_amdgcn_mfma_f32_16x16x32_f16(tw, bQb, z4, 0, 0, 0);

        #pragma unroll
        for (int e = 0; e < 4; ++e) {
            const float A  = rA[e],  Bv = rB[e];
            const float Qa = rQa[e], Qb = rQb[e];
            const float u = A * A, v = Bv * Bv;
            const float t1 = u - v;                              // 4*mu1*mu2
            const float t2 = u + v;                              // 2*(mu1^2+mu2^2)
            const float num1 = fmaf(0.5f, t1, C1);
            const float den1 = fmaf(0.5f, t2, C1);
            const float num2 = fmaf(0.5f, (Qa - Qb) - t1, C2);   // 2*sigma12 + C2
            const float den2 = fmaf(0.5f, (Qa + Qb) - t2, C2);   // sig1+sig2 + C2
            local += (num1 * num2) * __builtin_amdgcn_rcpf(den1 * den2);
        }
    }

    #pragma unroll
    for (int off = 32; off > 0; off >>= 1) local += __shfl_down(local, off, 64);
    if (lane == 0) red[wave] = local;
    __syncthreads();
    if (tid == 0) {
        float s = 0.f;
        #pragma unroll
        for (int wv = 0; wv < 8; ++wv) s += red[wv];
        part[id] = s;
    }
}

__global__ __launch_bounds__(512)
void ssim_final(const float* __restrict__ part, float* __restrict__ out)
{
    __shared__ double red[8];
    const int tid = threadIdx.x;
    double s = 0.0;
    for (int i = tid; i < NBLK; i += 512) s += (double)part[i];
    #pragma unroll
    for (int off = 32; off > 0; off >>= 1) s += __shfl_down(s, off, 64);
    if ((tid & 63) == 0) red[tid >> 6] = s;
    __syncthreads();
    if (tid == 0) {
        double t = 0.0;
        #pragma unroll
        for (int wv = 0; wv < 8; ++wv) t += red[wv];
        out[0] = (float)(1.0 - t / NTOT);
    }
}

extern "C" void kernel_launch(void* const* d_in, const int* in_sizes, int n_in,
                              void* d_out, int out_size, void* d_ws, size_t ws_size,
                              hipStream_t stream)
{
    const float* img1 = (const float*)d_in[0];
    const float* img2 = (const float*)d_in[1];
    float* out = (float*)d_out;
    float* part = (float*)d_ws;   // NBLK floats, fully rewritten each call

    Wts wts;
    double wd[11], s = 0.0;
    for (int k = 0; k < 11; ++k) {
        const double d = (double)(k - 5);
        wd[k] = exp(-0.5 / (1.5 * 1.5) * d * d);
        s += wd[k];
    }
    for (int k = 0; k < 11; ++k) wts.w[k] = (float)(wd[k] / s);

    ssim_main<<<NBLK, 512, 0, stream>>>(img1, img2, part, wts);
    ssim_final<<<1, 512, 0, stream>>>(part, out);
}

// Round 8
// 268.732 us; speedup vs baseline: 1.7427x; 1.7427x over previous
//
#include <hip/hip_runtime.h>
#include <math.h>

typedef _Float16 f16;
typedef f16 f16x8 __attribute__((ext_vector_type(8)));
typedef float f32x4 __attribute__((ext_vector_type(4)));
typedef unsigned int u32;
typedef u32 u32x2 __attribute__((ext_vector_type(2)));

constexpr int H = 512, W = 512;
constexpr int TY = 16;                  // output rows per block
constexpr int TW = 256;                 // output cols per block
constexpr int NBANDS = H / TY;          // 32
constexpr int GXB = W / TW;             // 2
constexpr int NPLANES = 96;             // 32 batch * 3 ch
constexpr int NBLK = GXB * NBANDS * NPLANES;   // 6144
constexpr int NTILES_V = 17;            // halo col tiles: 272 >= 266 (extra cols hit zero weights, finite data)
constexpr int NTILES_H = TW / 16;       // 16
constexpr int VP = 280;                 // f16 pitch: 140 words == 12 (mod 32) -> 8 distinct bank starts
constexpr double NTOT = 25165824.0;
constexpr float C1 = 1.0e-4f;
constexpr float C2 = 9.0e-4f;

struct Wts { float w[11]; };

__device__ __forceinline__ u32 pk(float lo, float hi) {
    return __builtin_bit_cast(u32, __builtin_amdgcn_cvt_pkrtz(lo, hi));
}

// Vertical-conv tile via mfma(A=data, B=Toeplitz). Lane(tr,g) holds
// A[tr][k0+j] = pre[row y0-5+k0+j][halo col 16t+tr]. Zero-band rows k>=26
// (g==3, j>=2) multiply exactly-zero Toeplitz rows -> zero fragments, no loads.
// Fragments built with scalar f16 inserts (round-5 style, 52-VGPR profile) --
// round 7's u32-staging + launch_bounds(512,8) spilled 568 MB to scratch.
template<bool MASK, bool YEDGE>
__device__ __forceinline__ void stage_v(const float* __restrict__ p1,
                                        const float* __restrict__ p2,
                                        f16 (&vc)[4][TY][VP], const f16x8 tw,
                                        const int (&rowbase)[8], const float (&ymul)[8],
                                        int x, int t, int tr, int g, int k0)
{
    int xc = x; float xm = 1.f;
    if (MASK) {
        const bool xok = (unsigned)x < (unsigned)W;
        xc = xok ? x : 0;
        xm = xok ? 1.f : 0.f;
    }
    f16x8 fA, fB, fQa, fQb;
    #pragma unroll
    for (int j = 0; j < 8; ++j) {
        float a = 0.f, b = 0.f;
        if (k0 + j < 26) {                 // per-lane exec mask; skips 6 rows on g==3
            float v1 = p1[rowbase[j] + xc];
            float v2 = p2[rowbase[j] + xc];
            if (MASK || YEDGE) {
                float m = 1.f;
                if (MASK)  m = xm;
                if (YEDGE) m *= ymul[j];
                v1 *= m; v2 *= m;
            }
            a = v1 + v2; b = v1 - v2;
        }
        fA[j]  = (f16)a;       fB[j]  = (f16)b;
        fQa[j] = (f16)(a * a); fQb[j] = (f16)(b * b);
    }

    const f32x4 z4 = { 0.f, 0.f, 0.f, 0.f };
    const f32x4 dA  = __builtin_amdgcn_mfma_f32_16x16x32_f16(fA,  tw, z4, 0, 0, 0);
    const f32x4 dB  = __builtin_amdgcn_mfma_f32_16x16x32_f16(fB,  tw, z4, 0, 0, 0);
    const f32x4 dQa = __builtin_amdgcn_mfma_f32_16x16x32_f16(fQa, tw, z4, 0, 0, 0);
    const f32x4 dQb = __builtin_amdgcn_mfma_f32_16x16x32_f16(fQb, tw, z4, 0, 0, 0);

    // D lane(tr,g) reg i -> output row tr, halo col 16t+4g+i (refcheck-verified
    // rounds 5/7). One b64 store per plane.
    const int cb = 16 * t + 4 * g;
    { u32x2 v = { pk(dA[0],  dA[1]),  pk(dA[2],  dA[3])  }; *(u32x2*)&vc[0][tr][cb] = v; }
    { u32x2 v = { pk(dB[0],  dB[1]),  pk(dB[2],  dB[3])  }; *(u32x2*)&vc[1][tr][cb] = v; }
    { u32x2 v = { pk(dQa[0], dQa[1]), pk(dQa[2], dQa[3]) }; *(u32x2*)&vc[2][tr][cb] = v; }
    { u32x2 v = { pk(dQb[0], dQb[1]), pk(dQb[2], dQb[3]) }; *(u32x2*)&vc[3][tr][cb] = v; }
}

template<bool YEDGE>
__device__ __forceinline__ void stage_v_all(const float* __restrict__ p1,
                                            const float* __restrict__ p2,
                                            f16 (&vc)[4][TY][VP], const f16x8 tw,
                                            int y0, int x0, int xb,
                                            int tr, int g, int k0, int wave)
{
    int rowbase[8]; float ymul[8];
    #pragma unroll
    for (int j = 0; j < 8; ++j) {
        const int y = y0 - 5 + k0 + j;
        if (YEDGE) {
            const bool yok = (unsigned)y < (unsigned)H;
            rowbase[j] = (yok ? y : 0) * W;
            ymul[j] = yok ? 1.f : 0.f;
        } else {
            rowbase[j] = y * W;
            ymul[j] = 1.f;
        }
    }
    const int mt = xb ? (NTILES_V - 1) : 0;   // the single x-masked tile
    for (int t = wave; t < NTILES_V; t += 8) {
        const int x = x0 + 16 * t + tr - 5;
        if (t == mt) stage_v<true,  YEDGE>(p1, p2, vc, tw, rowbase, ymul, x, t, tr, g, k0);
        else         stage_v<false, YEDGE>(p1, p2, vc, tw, rowbase, ymul, x, t, tr, g, k0);
    }
}

__global__ __launch_bounds__(512, 4)
void ssim_main(const float* __restrict__ img1, const float* __restrict__ img2,
               float* __restrict__ part, Wts wts)
{
    __shared__ __align__(16) f16 vc[4][TY][VP];   // 35,840 B -> 4 blocks/CU
    __shared__ __align__(16) f16 Tb[16][40];
    __shared__ float red[8];

    const int tid  = threadIdx.x;
    const int lane = tid & 63;
    const int wave = tid >> 6;
    const int tr   = lane & 15;
    const int g    = lane >> 4;
    const int k0   = g * 8;

    // Toeplitz T[idx][k] = w[k-idx] (zero band kills k>=26 garbage).
    for (int i = tid; i < 640; i += 512) {
        const int m = i / 40, k = i - m * 40, d = k - m;
        Tb[m][k] = (d >= 0 && d <= 10) ? (f16)wts.w[d] : (f16)0.0f;
    }
    __syncthreads();
    const f16x8 tw = *(const f16x8*)&Tb[tr][k0];

    // XCD swizzle: each XCD gets 12 contiguous planes (2 MB/plane-pair < 4 MB
    // L2) -> band halos and plane data reused in the local L2. Perf-only.
    const int id    = blockIdx.x;
    const int gb    = (id & 7) * (NBLK / 8) + (id >> 3);
    const int plane = gb >> 6;            // 64 blocks per plane
    const int rem   = gb & 63;
    const int band  = rem >> 1;
    const int xb    = rem & 1;

    const int y0 = band * TY;
    const int x0 = xb * TW;
    const size_t poff = (size_t)plane * (size_t)(H * W);
    const float* p1 = img1 + poff;
    const float* p2 = img2 + poff;

    if (band == 0 || band == NBANDS - 1)
        stage_v_all<true>(p1, p2, vc, tw, y0, x0, xb, tr, g, k0, wave);
    else
        stage_v_all<false>(p1, p2, vc, tw, y0, x0, xb, tr, g, k0, wave);
    __syncthreads();

    // Stage H: mfma(A=Toeplitz, B=vc rows) + SSIM map. Lane(tr,g) holds
    // B[k0+j][tr] = vc[row tr][cb+k0+j] -> one ds_read_b128 per plane.
    const f32x4 z4 = { 0.f, 0.f, 0.f, 0.f };
    float local = 0.f;
    #pragma unroll
    for (int i = 0; i < NTILES_H / 8; ++i) {
        const int cb = 16 * (wave + 8 * i);
        const f16x8 bA  = *(const f16x8*)&vc[0][tr][cb + k0];
        const f16x8 bB  = *(const f16x8*)&vc[1][tr][cb + k0];
        const f16x8 bQa = *(const f16x8*)&vc[2][tr][cb + k0];
        const f16x8 bQb = *(const f16x8*)&vc[3][tr][cb + k0];
        const f32x4 rA  = __builtin_amdgcn_mfma_f32_16x16x32_f16(tw, bA,  z4, 0, 0, 0);
        const f32x4 rB  = __builtin_amdgcn_mfma_f32_16x16x32_f16(tw, bB,  z4, 0, 0, 0);
        const f32x4 rQa = __builtin_amdgcn_mfma_f32_16x16x32_f16(tw, bQa, z4, 0, 0, 0);
        const f32x4 rQb = __builtin_amdgcn_mfma_f32_16x16x32_f16(tw, bQb, z4, 0, 0, 0);

        #pragma unroll
        for (int e = 0; e < 4; ++e) {
            const float A  = rA[e],  Bv = rB[e];
            const float Qa = rQa[e], Qb = rQb[e];
            const float u = A * A, v = Bv * Bv;
            const float t1 = u - v;                              // 4*mu1*mu2
            const float t2 = u + v;                              // 2*(mu1^2+mu2^2)
            const float num1 = fmaf(0.5f, t1, C1);
            const float den1 = fmaf(0.5f, t2, C1);
            const float num2 = fmaf(0.5f, (Qa - Qb) - t1, C2);   // 2*sigma12 + C2
            const float den2 = fmaf(0.5f, (Qa + Qb) - t2, C2);   // sig1+sig2 + C2
            local += (num1 * num2) * __builtin_amdgcn_rcpf(den1 * den2);
        }
    }

    #pragma unroll
    for (int off = 32; off > 0; off >>= 1) local += __shfl_down(local, off, 64);
    if (lane == 0) red[wave] = local;
    __syncthreads();
    if (tid == 0) {
        float s = 0.f;
        #pragma unroll
        for (int wv = 0; wv < 8; ++wv) s += red[wv];
        part[id] = s;
    }
}

__global__ __launch_bounds__(512)
void ssim_final(const float* __restrict__ part, float* __restrict__ out)
{
    __shared__ double red[8];
    const int tid = threadIdx.x;
    double s = 0.0;
    for (int i = tid; i < NBLK; i += 512) s += (double)part[i];
    #pragma unroll
    for (int off = 32; off > 0; off >>= 1) s += __shfl_down(s, off, 64);
    if ((tid & 63) == 0) red[tid >> 6] = s;
    __syncthreads();
    if (tid == 0) {
        double t = 0.0;
        #pragma unroll
        for (int wv = 0; wv < 8; ++wv) t += red[wv];
        out[0] = (float)(1.0 - t / NTOT);
    }
}

extern "C" void kernel_launch(void* const* d_in, const int* in_sizes, int n_in,
                              void* d_out, int out_size, void* d_ws, size_t ws_size,
                              hipStream_t stream)
{
    const float* img1 = (const float*)d_in[0];
    const float* img2 = (const float*)d_in[1];
    float* out = (float*)d_out;
    float* part = (float*)d_ws;   // NBLK floats, fully rewritten each call

    Wts wts;
    double wd[11], s = 0.0;
    for (int k = 0; k < 11; ++k) {
        const double d = (double)(k - 5);
        wd[k] = exp(-0.5 / (1.5 * 1.5) * d * d);
        s += wd[k];
    }
    for (int k = 0; k < 11; ++k) wts.w[k] = (float)(wd[k] / s);

    ssim_main<<<NBLK, 512, 0, stream>>>(img1, img2, part, wts);
    ssim_final<<<1, 512, 0, stream>>>(part, out);
}